// Round 2
// 22254.561 us; speedup vs baseline: 1.1424x; 1.1424x over previous
//
#include <hip/hip_runtime.h>
#include <cstdint>

#define T_LEN 16384
#define X_DIM 256
#define H_DIM 1024
#define NREP  8                  // h-buffer replicas (slice spreading)
#define SLOT_U32 1024            // unpadded: col c lives at dword c (no LDS -> no pad needed)
#define REP_U32  (2 * SLOT_U32)  // ping-pong slots per replica
#define FLAG_OFF (NREP * REP_U32)  // 16384 dwords = 64 KB (< proven 80 KB ws footprint)

typedef unsigned int u32;
typedef u32   u32x4 __attribute__((ext_vector_type(4)));
typedef float f32x4 __attribute__((ext_vector_type(4)));

// ---------------------------------------------------------------------------
// Device-scope coherent ops (sc0 sc1 -> MALL is the coherence point; per-XCD
// L2s are not cross-coherent). Every published dword self-validates via a
// 2-bit step tag in its mantissa LSBs -> only 4 B atomicity required.
// Protocol (replicas / ping-pong slots / mod-4 tags) is HW-proven from the
// previous session; this version changes only WHO polls (every wave, not
// just wave0) and the slot layout (unpadded).
// ---------------------------------------------------------------------------
__device__ __forceinline__ void coh_store4(u32* p, u32x4 v) {
  asm volatile("global_store_dwordx4 %0, %1, off sc0 sc1" :: "v"(p), "v"(v) : "memory");
}
__device__ __forceinline__ void coh_store1(u32* p, u32 v) {
  asm volatile("global_store_dword %0, %1, off sc0 sc1" :: "v"(p), "v"(v) : "memory");
}
__device__ __forceinline__ u32 coh_load1(const u32* p) {
  u32 v;
  asm volatile("global_load_dword %0, %1, off sc0 sc1\n\ts_waitcnt vmcnt(0)"
               : "=v"(v) : "v"(p) : "memory");
  return v;
}
// Poll one 64 B group (16 dwords) = the 16 h values this lane consumes.
// The vmcnt(0) also drains this wave's prior publish stores -> same-dword
// store ordering across slot reuse is guaranteed every iteration.
__device__ __forceinline__ void poll_group(const u32* p, u32x4& a, u32x4& b,
                                           u32x4& c, u32x4& d) {
  asm volatile(
      "global_load_dwordx4 %0, %4, off sc0 sc1\n\t"
      "global_load_dwordx4 %1, %4, off offset:16 sc0 sc1\n\t"
      "global_load_dwordx4 %2, %4, off offset:32 sc0 sc1\n\t"
      "global_load_dwordx4 %3, %4, off offset:48 sc0 sc1\n\t"
      "s_waitcnt vmcnt(0)"
      : "=&v"(a), "=&v"(b), "=&v"(c), "=&v"(d) : "v"(p) : "memory");
}

__device__ __forceinline__ float fast_tanh(float x) {
  x = fminf(9.0f, fmaxf(-9.0f, x));
  const float e = __builtin_amdgcn_exp2f(x * 2.8853900817779268f); // 2*log2(e)
  return (e - 1.0f) * __builtin_amdgcn_rcpf(e + 1.0f);
}

// ---------------------------------------------------------------------------
// 64-lane all-reduce: 4x DPP row_ror adds (within-16 all-reduce, pure VALU)
// + 2x __shfl_xor (16, 32) for the cross-row halves. The shfl tail is the
// exact cross-lane op the HW-proven previous kernel used (de-risked vs the
// permlane32_swap variant that may have miscompiled/hung last round).
// ---------------------------------------------------------------------------
template <int CTRL>
__device__ __forceinline__ float ror_add(float x) {
  const int y = __builtin_amdgcn_update_dpp(0, __float_as_int(x), CTRL, 0xF, 0xF, false);
  return x + __int_as_float(y);
}
__device__ __forceinline__ float redux64(float x) {
  x = ror_add<0x121>(x);   // row_ror:1
  x = ror_add<0x122>(x);   // row_ror:2
  x = ror_add<0x124>(x);   // row_ror:4
  x = ror_add<0x128>(x);   // row_ror:8  -> all lanes hold 16-lane row sum
  x += __shfl_xor(x, 16, 64);
  x += __shfl_xor(x, 32, 64);
  return x;
}

// ---------------------------------------------------------------------------
// Kernel 0: seed slot 0 of every replica with h0 (tag 0) and zero the filler
// done-flag. Poison 0xAAAAAAAA has tag LSBs 0b10: slot0 is fully overwritten
// here (tags {0,2} safe), slot1 stale content from a previous replay carries
// tag 3 (t=16382 publish) while t=1 expects tag 1 -> no false accept.
// ---------------------------------------------------------------------------
__global__ void hinit(const float* __restrict__ h0, u32* __restrict__ ws) {
  const int i = threadIdx.x;              // 256 threads x 4 cols
  const f32x4 h = *(const f32x4*)(h0 + i * 4);
  u32x4 v;
  v.x = __float_as_uint(h[0]) & ~3u;
  v.y = __float_as_uint(h[1]) & ~3u;
  v.z = __float_as_uint(h[2]) & ~3u;
  v.w = __float_as_uint(h[3]) & ~3u;
  const int idx = i * 4;                  // linear layout, 16 B aligned
#pragma unroll
  for (int rep = 0; rep < NREP; ++rep)
    coh_store4(ws + (size_t)rep * REP_U32 + idx, v);
  if (i < 2) coh_store1(ws + FLAG_OFF + i, 0u);  // done flag + spare
}

// ---------------------------------------------------------------------------
// Kernel 1: Bx_c = x @ B^T + c into d_out (scan reads bx[t] for rows it later
// overwrites, read-before-write within the same wave). Unchanged.
// ---------------------------------------------------------------------------
__global__ __launch_bounds__(256) void gemm_bx(const float* __restrict__ x,
                                               const float* __restrict__ Bm,
                                               const float* __restrict__ c,
                                               float* __restrict__ out) {
  __shared__ float xs[64][68];
  __shared__ float bs[64][68];

  const int tid = threadIdx.x;
  const int t0  = blockIdx.x * 64;
  const int h0  = blockIdx.y * 64;
  const int lr  = tid >> 4;
  const int lc  = tid & 15;

  float acc[4][4] = {};

  for (int kb = 0; kb < X_DIM; kb += 64) {
    const int kk  = (tid & 15) * 4;
    const int tt0 = tid >> 4;
#pragma unroll
    for (int i = 0; i < 4; ++i) {
      const int tt = tt0 + i * 16;
      const f32x4 xv = *(const f32x4*)(x  + (size_t)(t0 + tt) * X_DIM + kb + kk);
      const f32x4 bv = *(const f32x4*)(Bm + (size_t)(h0 + tt) * X_DIM + kb + kk);
#pragma unroll
      for (int q = 0; q < 4; ++q) {
        xs[kk + q][tt] = xv[q];
        bs[kk + q][tt] = bv[q];
      }
    }
    __syncthreads();

#pragma unroll 8
    for (int k = 0; k < 64; ++k) {
      const f32x4 xv = *(const f32x4*)&xs[k][lr * 4];
      const f32x4 bv = *(const f32x4*)&bs[k][lc * 4];
#pragma unroll
      for (int i = 0; i < 4; ++i)
#pragma unroll
        for (int j = 0; j < 4; ++j)
          acc[i][j] = fmaf(xv[i], bv[j], acc[i][j]);
    }
    __syncthreads();
  }

  const f32x4 cv = *(const f32x4*)(c + h0 + lc * 4);
#pragma unroll
  for (int i = 0; i < 4; ++i) {
    f32x4 o;
#pragma unroll
    for (int j = 0; j < 4; ++j) o[j] = acc[i][j] + cv[j];
    *(f32x4*)(out + (size_t)(t0 + lr * 4 + i) * H_DIM + h0 + lc * 4) = o;
  }
}

// ---------------------------------------------------------------------------
// Kernel 2: 256 blocks. Blocks 0-63 = scan workers, 4 independent waves each.
// Every wave polls its replica directly -> lane l receives h[16l..16l+15] in
// registers; no LDS relay, no vtag spin, no ds_read traffic, no barriers in
// the worker path. Wave gw owns rows 4gw..4gw+3; lane l holds A[4 rows][cols
// 16l..16l+15]; partial dots all-reduced across 64 lanes (DPP ror + shfl).
// Skew proof: a wave publishing t+1 validated ALL 64 groups of h(t) (one per
// lane) -> every wave finished step t-1 -> nobody still polls the (slot,tag)
// being overwritten. Per-iteration vmcnt(0) in poll_group orders same-dword
// publishes across the 8-step (slot,tag) reuse period.
// DEADMAN: poll budget 2^20 iterations/wave (~15-30x normal total). On
// expiry: raise done-flag, return -> test fails fast with absmax instead of
// a watchdog-killed container (diagnosable signal).
// Blocks 64-255 = DVFS fillers (unchanged, hard-capped).
// ---------------------------------------------------------------------------
__global__ __launch_bounds__(256) void rnn_scan(const float* __restrict__ A_raw,
                                                float* __restrict__ out,
                                                u32* __restrict__ ws) {
  const int tid = threadIdx.x;

  if (blockIdx.x >= 64) {
    // ---- filler: keep the DPM governor at high clock ----
    const u32* flag = ws + FLAG_OFF;
    float f0 = 0.f, f1 = 0.f, f2 = 0.f, f3 = 0.f;
    float f4 = 0.f, f5 = 0.f, f6 = 0.f, f7 = 0.f;
    const float m = 1.0000001f, ad = 1e-9f;
    for (int outer = 0; outer < 32768; ++outer) {   // hard cap ~56 ms @2.4GHz
      if (coh_load1(flag) != 0u) break;
      for (int i = 0; i < 256; ++i) {               // ~4096 cyc of VALU burn
        f0 = fmaf(f0, m, ad); f1 = fmaf(f1, m, ad);
        f2 = fmaf(f2, m, ad); f3 = fmaf(f3, m, ad);
        f4 = fmaf(f4, m, ad); f5 = fmaf(f5, m, ad);
        f6 = fmaf(f6, m, ad); f7 = fmaf(f7, m, ad);
      }
    }
    // DCE guard (condition is never true; compiler can't prove it).
    if (f0 + f1 + f2 + f3 + f4 + f5 + f6 + f7 == 123456.789f && tid == 0)
      coh_store1(ws + FLAG_OFF + 1, 1u);
    return;
  }

  // ---- worker wave ----
  const int lane    = tid & 63;
  const int wv      = tid >> 6;
  const int wg      = blockIdx.x;
  const int gw      = wg * 4 + wv;      // global wave id 0..255
  const int rowbase = gw * 4;
  const int r       = lane & 3;
  const int row     = rowbase + r;      // this lane's output row (lanes mod 4)

  // A fragment: a[rr][k] = 0.1*A_raw[rowbase+rr][16*lane+k] + 0.9*(col==row).
  float a[4][16];
#pragma unroll
  for (int rr = 0; rr < 4; ++rr) {
#pragma unroll
    for (int k4 = 0; k4 < 4; ++k4) {
      const f32x4 v = *(const f32x4*)(A_raw + (size_t)(rowbase + rr) * H_DIM +
                                      lane * 16 + k4 * 4);
#pragma unroll
      for (int q = 0; q < 4; ++q) {
        const int col = lane * 16 + k4 * 4 + q;
        a[rr][k4 * 4 + q] = 0.1f * v[q] + (col == rowbase + rr ? 0.9f : 0.0f);
      }
    }
  }

  u32* hbuf = ws;
  // Each wave polls one replica; 32 waves per replica, balanced.
  const u32* ppoll0 = hbuf + (size_t)(gw & (NREP - 1)) * REP_U32 + 16 * lane;
  // Publish pointer for lanes 0..31: replica lane>>2, row-class lane&3.
  u32* pub = hbuf + (size_t)(lane >> 2) * REP_U32 + rowbase + r;

  // 2-deep bx prefetch: out[t] rows are only overwritten by THIS wave at
  // step t -> reading out[t+2] at step t is read-before-write, same wave.
  float bx_val = out[(size_t)0 * H_DIM + row];
  float bx_n1  = out[(size_t)1 * H_DIM + row];

  int  dead    = 1 << 20;   // total poll budget (~15-30x normal)
  bool timeout = false;

  for (int t = 0; t < T_LEN; ++t) {
    // Poll own group of slot t&1 until all 16 dwords carry tag t&3.
    // Satisfied lanes drop out (exec-masked); wave lockstep re-converges all
    // 64 lanes before the reduce.
    const u32 tag = (u32)(t & 3);
    const u32* p  = ppoll0 + (t & 1) * SLOT_U32;
    u32x4 hA, hB, hC, hD;
    for (;;) {
      poll_group(p, hA, hB, hC, hD);
      const u32 m = (hA.x ^ tag) | (hA.y ^ tag) | (hA.z ^ tag) | (hA.w ^ tag)
                  | (hB.x ^ tag) | (hB.y ^ tag) | (hB.z ^ tag) | (hB.w ^ tag)
                  | (hC.x ^ tag) | (hC.y ^ tag) | (hC.z ^ tag) | (hC.w ^ tag)
                  | (hD.x ^ tag) | (hD.y ^ tag) | (hD.z ^ tag) | (hD.w ^ tag);
      if ((m & 3u) == 0u) break;
      if (--dead == 0) { timeout = true; break; }
    }
    if (__any(timeout)) {
      if (lane == 0) coh_store1(ws + FLAG_OFF, 1u);  // fail fast, release fillers
      return;
    }

    // Issue bx(t+2) now; ~2 full step periods to cover HBM latency.
    const int tn2 = (t + 2 < T_LEN) ? t + 2 : t;
    const float bx_n2 = out[(size_t)tn2 * H_DIM + row];

    // Partial dots straight from poll registers (tag bits left in mantissa,
    // rel err <= 2^-22 -- same as proven version).
    const f32x4 f0 = __builtin_bit_cast(f32x4, hA);
    const f32x4 f1 = __builtin_bit_cast(f32x4, hB);
    const f32x4 f2 = __builtin_bit_cast(f32x4, hC);
    const f32x4 f3 = __builtin_bit_cast(f32x4, hD);
    float ac0 = 0.f, ac1 = 0.f, ac2 = 0.f, ac3 = 0.f;
#pragma unroll
    for (int j = 0; j < 4; ++j) {
      ac0 = fmaf(a[0][j], f0[j], ac0); ac1 = fmaf(a[1][j], f0[j], ac1);
      ac2 = fmaf(a[2][j], f0[j], ac2); ac3 = fmaf(a[3][j], f0[j], ac3);
    }
#pragma unroll
    for (int j = 0; j < 4; ++j) {
      ac0 = fmaf(a[0][4 + j], f1[j], ac0); ac1 = fmaf(a[1][4 + j], f1[j], ac1);
      ac2 = fmaf(a[2][4 + j], f1[j], ac2); ac3 = fmaf(a[3][4 + j], f1[j], ac3);
    }
#pragma unroll
    for (int j = 0; j < 4; ++j) {
      ac0 = fmaf(a[0][8 + j], f2[j], ac0); ac1 = fmaf(a[1][8 + j], f2[j], ac1);
      ac2 = fmaf(a[2][8 + j], f2[j], ac2); ac3 = fmaf(a[3][8 + j], f2[j], ac3);
    }
#pragma unroll
    for (int j = 0; j < 4; ++j) {
      ac0 = fmaf(a[0][12 + j], f3[j], ac0); ac1 = fmaf(a[1][12 + j], f3[j], ac1);
      ac2 = fmaf(a[2][12 + j], f3[j], ac2); ac3 = fmaf(a[3][12 + j], f3[j], ac3);
    }

    // 64-lane all-reduce of the 4 row sums (independent chains -> ILP).
    ac0 = redux64(ac0);
    ac1 = redux64(ac1);
    ac2 = redux64(ac2);
    ac3 = redux64(ac3);

    float accr = ac0;
    if (r == 1) accr = ac1;
    if (r == 2) accr = ac2;
    if (r == 3) accr = ac3;
    const float v = fast_tanh(accr + bx_val);
    bx_val = bx_n1;
    bx_n1  = bx_n2;

    const u32 nt = (u32)((t + 1) & 3);
    if (lane < 4 * NREP) {
      // lanes 0..31: publish to replica lane>>2, row-class lane&3.
      coh_store1(pub + (size_t)((t + 1) & 1) * SLOT_U32,
                 (__float_as_uint(v) & ~3u) | nt);
    } else if (lane < 4 * NREP + 4) {
      // lanes 32..35: clean output write (bx already consumed this step).
      out[(size_t)t * H_DIM + row] = v;
    }
  }

  if (gw == 0 && lane == 0) coh_store1(ws + FLAG_OFF, 1u);  // release fillers
}

// ---------------------------------------------------------------------------
extern "C" void kernel_launch(void* const* d_in, const int* in_sizes, int n_in,
                              void* d_out, int out_size, void* d_ws, size_t ws_size,
                              hipStream_t stream) {
  const float* x    = (const float*)d_in[0];  // (T, X)
  const float* h0   = (const float*)d_in[1];  // (H,)
  const float* Araw = (const float*)d_in[2];  // (H, H)
  const float* B    = (const float*)d_in[3];  // (H, X)
  const float* c    = (const float*)d_in[4];  // (H,)
  float* out = (float*)d_out;                 // (T, H)
  u32* ws    = (u32*)d_ws;                    // 64 KB hbuf + flag dwords

  hinit<<<1, 256, 0, stream>>>(h0, ws);
  dim3 g(T_LEN / 64, H_DIM / 64);
  gemm_bx<<<g, 256, 0, stream>>>(x, B, c, out);
  rnn_scan<<<256, 256, 0, stream>>>(Araw, out, ws);
}